// Round 7
// baseline (197.307 us; speedup 1.0000x reference)
//
#include <hip/hip_runtime.h>

#define B_ROWS 8192
#define BMASK  8191
#define DIM    128
#define BLK64  16384      // bytes per packed 64-row block (64*128*2)
#define NB     384        // grid; co-residency guaranteed (>=2 blocks/CU = 512 slots)

typedef __attribute__((ext_vector_type(8)))  __bf16 bf16x8;
typedef __attribute__((ext_vector_type(16))) float  f32x16;

// sqrt(log2(e)/0.07) folded symmetrically into both row normalizations.
#define RBSCALE 4.5398159f

// Single fused kernel:
//   phase 1: blocks 0..255 pack/normalize 64 rows each (fp32 -> scaled bf16, k-major granules)
//   grid spin-barrier (all NB blocks resident by construction)
//   phase 2: panel p = b&31 owns rows [256p, 256p+256) in REGISTERS (64 rows/wave);
//            chunk s = b>>5 of that panel's fused z0+z1 tile list; B tiles (64 cols)
//            double-buffered via global_load_lds.
__global__ __launch_bounds__(256, 2)
void fused_kernel(const float* __restrict__ e1, const float* __restrict__ e2,
                  char* __restrict__ P1, char* __restrict__ P2,
                  float* __restrict__ acc, float* __restrict__ out) {
    __shared__ __align__(16) __bf16 Bbuf[2][8192];   // 2 x 16 KB
    __shared__ float red[2][4];

    const int tid = threadIdx.x;
    const int b   = blockIdx.x;

    // ---------------- phase 1: pack + normalize ----------------
    if (b < 256) {
        const float* src; char* dst; int rb;
        if (b < 128) { src = e1; dst = P1; rb = b; }
        else         { src = e2; dst = P2; rb = b - 128; }
        const int rr = tid >> 2, q = tid & 3;          // row 0..63, k-quarter 0..3
        const float* rp = src + (size_t)(rb * 64 + rr) * DIM + q * 32;
        float4 f[8]; float ss = 0.f;
#pragma unroll
        for (int j = 0; j < 8; ++j) {
            f[j] = ((const float4*)rp)[j];
            ss += f[j].x*f[j].x + f[j].y*f[j].y + f[j].z*f[j].z + f[j].w*f[j].w;
        }
        ss += __shfl_xor(ss, 1); ss += __shfl_xor(ss, 2);   // 4 lanes per row
        const float rs = RBSCALE / sqrtf(ss);
        char* db = dst + (size_t)rb * BLK64;
#pragma unroll
        for (int j = 0; j < 4; ++j) {
            bf16x8 v; float4 a = f[2*j], c = f[2*j+1];
            v[0]=(__bf16)(a.x*rs); v[1]=(__bf16)(a.y*rs); v[2]=(__bf16)(a.z*rs); v[3]=(__bf16)(a.w*rs);
            v[4]=(__bf16)(c.x*rs); v[5]=(__bf16)(c.y*rs); v[6]=(__bf16)(c.z*rs); v[7]=(__bf16)(c.w*rs);
            *(bf16x8*)(db + (size_t)(q*4 + j)*1024 + (size_t)rr*16) = v;
        }
    }

    // ---------------- grid spin-barrier ----------------
    unsigned* spin = (unsigned*)(acc + 2);
    __syncthreads();
    if (tid == 0) {
        __threadfence();                    // release phase-1 writes device-wide
        atomicAdd(spin, 1u);
        while (__hip_atomic_load(spin, __ATOMIC_ACQUIRE, __HIP_MEMORY_SCOPE_AGENT) < NB)
            __builtin_amdgcn_s_sleep(1);
    }
    __syncthreads();
    __threadfence();                        // acquire for all threads

    // ---------------- phase 2: tile mapping ----------------
    const int p  = b & 31;                  // 256-row panel
    const int s  = b >> 5;                  // chunk 0..11
    const int i0 = 256 * p;
    const int mx  = (4 * p > 4) ? 4 * p : 4;
    const int cnt = 132 - mx;               // z0 tiles in this panel
    const int n_p = cnt + 128;              // + z1 tiles
    const int m_p = (n_p + 11) / 12;
    const int t0  = s * m_p;
    const int t1  = (t0 + m_p < n_p) ? (t0 + m_p) : n_p;

    // tile t -> (z0?, c0, masked, src)
    auto tile_info = [&](int t, int& c0, bool& msk, bool& isz0, const char*& src) {
        if (t < cnt) {
            int kk = (t < 3) ? (t + 1) : (mx + t - 3);
            c0  = (i0 + 64 * kk) & BMASK;
            msk = (kk <= 3) || (kk == 128) || (kk >= 4 * p && kk <= 4 * p + 7);
            isz0 = true; src = P1;
        } else {
            c0 = 64 * (t - cnt); msk = false; isz0 = false; src = P2;
        }
    };

    const int w  = tid >> 6, lane = tid & 63;
    const int l  = lane & 31, h = lane >> 5;

    float s0 = 0.f, s1 = 0.f;

    if (t0 < t1) {
        // ---- A panel -> registers: wave w owns rows i0 + 64w + [0,64) = packed block 4p+w ----
        bf16x8 af[2][8];
        {
            const char* ap = P1 + (size_t)(4 * p + w) * BLK64;
#pragma unroll
            for (int g = 0; g < 2; ++g)
#pragma unroll
                for (int sc = 0; sc < 8; ++sc)
                    af[g][sc] = *(const bf16x8*)(ap + (size_t)(sc * 2 + h) * 1024
                                                    + (size_t)(g * 32 + l) * 16);
        }

        auto stage = [&](int bufi, int t) {
            int c0; bool msk, isz0; const char* src;
            tile_info(t, c0, msk, isz0, src);
            const char* gp = src + (size_t)(c0 >> 6) * BLK64 + (size_t)tid * 16;
            char*       lp = (char*)&Bbuf[bufi][0] + (size_t)tid * 16;
#pragma unroll
            for (int r = 0; r < 4; ++r)
                __builtin_amdgcn_global_load_lds(
                    (const __attribute__((address_space(1))) unsigned int*)(gp + r * 4096),
                    (__attribute__((address_space(3))) unsigned int*)(lp + r * 4096),
                    16, 0, 0);
        };

        const int i00 = i0 + 64 * w + 4 * h;     // lane's row base

        stage(0, t0);
        int cur = 0;
        for (int t = t0; t < t1; ++t) {
            __syncthreads();                      // buf[cur] staged; prev compute done
            if (t + 1 < t1) stage(cur ^ 1, t + 1);

            f32x16 a00, a01, a10, a11;
#pragma unroll
            for (int r = 0; r < 16; ++r) { a00[r] = 0.f; a01[r] = 0.f; a10[r] = 0.f; a11[r] = 0.f; }

            const char* bb = (const char*)&Bbuf[cur][0] + (size_t)h * 1024 + (size_t)l * 16;
#pragma unroll
            for (int sc = 0; sc < 8; ++sc) {
                bf16x8 b0 = *(const bf16x8*)(bb + (size_t)sc * 2048);
                bf16x8 b1 = *(const bf16x8*)(bb + (size_t)sc * 2048 + 512);
                a00 = __builtin_amdgcn_mfma_f32_32x32x16_bf16(af[0][sc], b0, a00, 0, 0, 0);
                a01 = __builtin_amdgcn_mfma_f32_32x32x16_bf16(af[0][sc], b1, a01, 0, 0, 0);
                a10 = __builtin_amdgcn_mfma_f32_32x32x16_bf16(af[1][sc], b0, a10, 0, 0, 0);
                a11 = __builtin_amdgcn_mfma_f32_32x32x16_bf16(af[1][sc], b1, a11, 0, 0, 0);
            }

            int c0; bool msk, isz0; const char* src;
            tile_info(t, c0, msk, isz0, src);

            float ts = 0.f;
            if (msk) {
#pragma unroll
                for (int g = 0; g < 2; ++g) {
                    const f32x16& ac0 = g ? a10 : a00;
                    const f32x16& ac1 = g ? a11 : a01;
#pragma unroll
                    for (int r = 0; r < 16; ++r) {
                        int i = i00 + g * 32 + (r & 3) + 8 * (r >> 2);
                        int c = c0 + l;
                        int d = (c - i) & BMASK;
                        ts += (d > i) ? exp2f(ac0[r]) : 0.f;
                        int c2 = c + 32;
                        int d2 = (c2 - i) & BMASK;
                        ts += (d2 > i) ? exp2f(ac1[r]) : 0.f;
                    }
                }
            } else {
#pragma unroll
                for (int r = 0; r < 16; ++r)
                    ts += exp2f(a00[r]) + exp2f(a01[r]) + exp2f(a10[r]) + exp2f(a11[r]);
            }
            if (isz0) s0 += ts; else s1 += ts;
            cur ^= 1;
        }
    }

    // ---------------- reduce + finalize ----------------
#pragma unroll
    for (int o = 32; o > 0; o >>= 1) {
        s0 += __shfl_down(s0, o);
        s1 += __shfl_down(s1, o);
    }
    if (lane == 0) { red[0][w] = s0; red[1][w] = s1; }
    __syncthreads();
    if (tid == 0) {
        atomicAdd(&acc[0], red[0][0] + red[0][1] + red[0][2] + red[0][3]);
        atomicAdd(&acc[1], red[1][0] + red[1][1] + red[1][2] + red[1][3]);
        __threadfence();
        unsigned prev = atomicAdd((unsigned*)(acc + 3), 1u);
        if (prev == (unsigned)(NB - 1)) {
            float l1 = atomicAdd(&acc[0], 0.f);
            float l2 = atomicAdd(&acc[1], 0.f);
            out[0] = -logf(l1 / l2);
        }
    }
}

extern "C" void kernel_launch(void* const* d_in, const int* in_sizes, int n_in,
                              void* d_out, int out_size, void* d_ws, size_t ws_size,
                              hipStream_t stream) {
    (void)in_sizes; (void)n_in; (void)out_size; (void)ws_size;
    const float* e1 = (const float*)d_in[0];
    const float* e2 = (const float*)d_in[1];
    float* out = (float*)d_out;
    char*  ws  = (char*)d_ws;

    float* acc = (float*)ws;                       // [0] l1, [1] l2, [2] spin, [3] done
    char*  p1  = ws + 4096;                        // 2 MB packed E1
    char*  p2  = ws + 4096 + 2097152;              // 2 MB packed E2

    hipMemsetAsync(acc, 0, 16, stream);
    fused_kernel<<<dim3(NB), dim3(256), 0, stream>>>(e1, e2, p1, p2, acc, out);
}

// Round 8
// 120.917 us; speedup vs baseline: 1.6318x; 1.6318x over previous
//
#include <hip/hip_runtime.h>

#define B_ROWS 8192
#define BMASK  8191
#define DIM    128
#define BLK64  16384          // bytes per packed 64-row block (64*128*2)
#define NB     1024           // blocks (4 waves each)
#define NWAVE  (NB * 4)
#define NSLOT  32
#define TTOT   24893          // total 64x64 wave-tiles (z0 pruned + z1 full)

typedef __attribute__((ext_vector_type(8)))  __bf16 bf16x8;
typedef __attribute__((ext_vector_type(16))) float  f32x16;

// sqrt(log2(e)/0.07) folded symmetrically into both row normalizations.
#define RBSCALE 4.5398159f

// z0 tiles for band b: count = 130 - max(b,2)
__device__ __forceinline__ int qcount(int band) {
    int m = (band < 2) ? 2 : band;
    return 258 - m;                     // (130 - m) z0 + 128 z1
}

// 64 rows per block: norm -> scale -> bf16 -> k-major packed layout
// packed[row>>6][granule=k/8][row&63][8 bf16]. Block 0 zeroes slot array + counter.
__global__ __launch_bounds__(256)
void prep_kernel(const float* __restrict__ e1, const float* __restrict__ e2,
                 char* __restrict__ p1, char* __restrict__ p2,
                 float* __restrict__ acc) {
    if (blockIdx.x == 0 && threadIdx.x < 2 * NSLOT + 4) acc[threadIdx.x] = 0.f;
    const int rb = blockIdx.x;            // 64-row block id, 0..255
    const float* src; char* dst; int rb_loc;
    if (rb < 128) { src = e1; dst = p1; rb_loc = rb; }
    else          { src = e2; dst = p2; rb_loc = rb - 128; }

    const int t  = threadIdx.x;
    const int rr = t >> 2;                // row within block, 0..63
    const int q  = t & 3;                 // quarter of the k-dim, 32 floats each

    const float* rp = src + (size_t)(rb_loc * 64 + rr) * DIM + q * 32;
    float4 f[8];
    float ss = 0.f;
#pragma unroll
    for (int j = 0; j < 8; ++j) {
        f[j] = ((const float4*)rp)[j];
        ss += f[j].x * f[j].x + f[j].y * f[j].y + f[j].z * f[j].z + f[j].w * f[j].w;
    }
    ss += __shfl_xor(ss, 1);
    ss += __shfl_xor(ss, 2);
    const float rbn = RBSCALE / sqrtf(ss);

    char* db = dst + (size_t)rb_loc * BLK64;
#pragma unroll
    for (int j = 0; j < 4; ++j) {
        bf16x8 v;
        float4 a = f[2 * j], b = f[2 * j + 1];
        v[0] = (__bf16)(a.x * rbn); v[1] = (__bf16)(a.y * rbn);
        v[2] = (__bf16)(a.z * rbn); v[3] = (__bf16)(a.w * rbn);
        v[4] = (__bf16)(b.x * rbn); v[5] = (__bf16)(b.y * rbn);
        v[6] = (__bf16)(b.z * rbn); v[7] = (__bf16)(b.w * rbn);
        *(bf16x8*)(db + (size_t)(q * 4 + j) * 1024 + (size_t)rr * 16) = v;
    }
}

// Barrier-free pair kernel: each wave owns a 64-row A band in registers and walks
// ~6 consecutive 64x64 tiles of the fused (z0-pruned + z1) tile list, loading B
// fragments straight global->VGPR (L2-resident 2 MB packed arrays). No __syncthreads
// in the hot loop; latency hidden by resident waves + in-wave vmcnt overlap.
__global__ __launch_bounds__(256, 2)
void pair_kernel(const char* __restrict__ P1, const char* __restrict__ P2,
                 float* __restrict__ acc, float* __restrict__ out) {
    __shared__ float red[2][4];

    const int tid  = threadIdx.x;
    const int b    = blockIdx.x;
    const int w    = tid >> 6, lane = tid & 63;
    const int l    = lane & 31, h = lane >> 5;
    const int W    = b * 4 + w;

    const int t_start = (int)(((long long)W       * TTOT) / NWAVE);
    const int t_end   = (int)(((long long)(W + 1) * TTOT) / NWAVE);

    // decode t_start -> (band, rem)
    int band = 0, rem = t_start;
    while (rem >= qcount(band)) { rem -= qcount(band); ++band; }

    float s0 = 0.f, s1 = 0.f;
    bf16x8 af[2][8];
    bool need_a = true;

    for (int t = t_start; t < t_end; ++t) {
        const int i0  = 64 * band;
        const int mx  = (band < 2) ? 2 : band;
        const int cnt0 = 130 - mx;

        if (need_a) {
            const char* ap = P1 + (size_t)band * BLK64;
#pragma unroll
            for (int g = 0; g < 2; ++g)
#pragma unroll
                for (int sc = 0; sc < 8; ++sc)
                    af[g][sc] = *(const bf16x8*)(ap + (size_t)(sc * 2 + h) * 1024
                                                    + (size_t)(g * 32 + l) * 16);
            need_a = false;
        }

        // tile decode
        const char* src; int c0; bool msk, isz0;
        if (rem < cnt0) {
            int e = (rem == 0) ? 64 : 64 * (mx + rem - 1);
            c0   = (i0 + e) & BMASK;
            msk  = (e < i0 + 128) || (e > B_ROWS - 64);
            isz0 = true;  src = P1;
        } else {
            c0 = 64 * (rem - cnt0); msk = false; isz0 = false; src = P2;
        }

        // B fragments straight from global (L2-resident packed tile, dense 16B/lane)
        const char* bp = src + (size_t)(c0 >> 6) * BLK64 + (size_t)h * 1024 + (size_t)l * 16;

        f32x16 a00, a01, a10, a11;
#pragma unroll
        for (int r = 0; r < 16; ++r) { a00[r] = 0.f; a01[r] = 0.f; a10[r] = 0.f; a11[r] = 0.f; }

#pragma unroll
        for (int sc = 0; sc < 8; ++sc) {
            bf16x8 b0 = *(const bf16x8*)(bp + (size_t)sc * 2048);
            bf16x8 b1 = *(const bf16x8*)(bp + (size_t)sc * 2048 + 512);
            a00 = __builtin_amdgcn_mfma_f32_32x32x16_bf16(af[0][sc], b0, a00, 0, 0, 0);
            a01 = __builtin_amdgcn_mfma_f32_32x32x16_bf16(af[0][sc], b1, a01, 0, 0, 0);
            a10 = __builtin_amdgcn_mfma_f32_32x32x16_bf16(af[1][sc], b0, a10, 0, 0, 0);
            a11 = __builtin_amdgcn_mfma_f32_32x32x16_bf16(af[1][sc], b1, a11, 0, 0, 0);
        }

        const int i00 = i0 + 4 * h;
        float ts = 0.f;
        if (msk) {
#pragma unroll
            for (int g = 0; g < 2; ++g) {
                const f32x16& ac0 = g ? a10 : a00;
                const f32x16& ac1 = g ? a11 : a01;
#pragma unroll
                for (int r = 0; r < 16; ++r) {
                    int i  = i00 + g * 32 + (r & 3) + 8 * (r >> 2);
                    int c  = c0 + l;
                    int d  = (c - i) & BMASK;
                    ts += (d > i) ? exp2f(ac0[r]) : 0.f;
                    int c2 = c + 32;
                    int d2 = (c2 - i) & BMASK;
                    ts += (d2 > i) ? exp2f(ac1[r]) : 0.f;
                }
            }
        } else {
#pragma unroll
            for (int r = 0; r < 16; ++r)
                ts += exp2f(a00[r]) + exp2f(a01[r]) + exp2f(a10[r]) + exp2f(a11[r]);
        }
        if (isz0) s0 += ts; else s1 += ts;

        // advance tile cursor
        if (++rem == qcount(band)) { rem = 0; ++band; need_a = true; }
    }

    // block reduce + slotted atomics
#pragma unroll
    for (int o = 32; o > 0; o >>= 1) {
        s0 += __shfl_down(s0, o);
        s1 += __shfl_down(s1, o);
    }
    if (lane == 0) { red[0][w] = s0; red[1][w] = s1; }
    __syncthreads();
    if (tid == 0) {
        int slot = b & (NSLOT - 1);
        atomicAdd(&acc[slot],         red[0][0] + red[0][1] + red[0][2] + red[0][3]);
        atomicAdd(&acc[NSLOT + slot], red[1][0] + red[1][1] + red[1][2] + red[1][3]);
        __threadfence();
        unsigned prev = atomicAdd((unsigned*)(acc + 2 * NSLOT), 1u);
        if (prev == (unsigned)(NB - 1)) {
            float l1 = 0.f, l2 = 0.f;
#pragma unroll
            for (int j = 0; j < NSLOT; ++j) {
                l1 += __hip_atomic_load(&acc[j],         __ATOMIC_RELAXED, __HIP_MEMORY_SCOPE_AGENT);
                l2 += __hip_atomic_load(&acc[NSLOT + j], __ATOMIC_RELAXED, __HIP_MEMORY_SCOPE_AGENT);
            }
            out[0] = -logf(l1 / l2);
        }
    }
}

extern "C" void kernel_launch(void* const* d_in, const int* in_sizes, int n_in,
                              void* d_out, int out_size, void* d_ws, size_t ws_size,
                              hipStream_t stream) {
    (void)in_sizes; (void)n_in; (void)out_size; (void)ws_size;
    const float* e1 = (const float*)d_in[0];
    const float* e2 = (const float*)d_in[1];
    float* out = (float*)d_out;
    char*  ws  = (char*)d_ws;

    float* acc = (float*)ws;                       // 2*NSLOT slots + done counter
    char*  p1  = ws + 4096;                        // 2 MB packed E1
    char*  p2  = ws + 4096 + 2097152;              // 2 MB packed E2

    prep_kernel<<<dim3(256), dim3(256), 0, stream>>>(e1, e2, p1, p2, acc);
    pair_kernel<<<dim3(NB), dim3(256), 0, stream>>>(p1, p2, acc, out);
}